// Round 8
// baseline (257.332 us; speedup 1.0000x reference)
//
#include <hip/hip_runtime.h>
#include <math.h>

#define Bn  65536
#define Dn  512
#define Kn  64
#define H1n 256
#define H2n 128
#define BM  64   // rows per block (1024 blocks, 8 waves; wave = 4 row-tiles)

typedef short bf16x8 __attribute__((ext_vector_type(8)));
typedef float floatx4 __attribute__((ext_vector_type(4)));

__device__ __forceinline__ unsigned short f2bf(float f) {
    unsigned u = __builtin_bit_cast(unsigned, f);
    u += 0x7FFF + ((u >> 16) & 1);   // round-to-nearest-even
    return (unsigned short)(u >> 16);
}

// packed f32x2 -> bf16x2 (RTNE), single VALU op
__device__ __forceinline__ unsigned cvt_pk_bf16(float lo, float hi) {
    unsigned r;
    asm("v_cvt_pk_bf16_f32 %0, %1, %2" : "=v"(r) : "v"(lo), "v"(hi));
    return r;
}

// ---- prep: fp32 weights -> bf16 FRAGMENT-MAJOR Bf[t][ks][lane][8] ----
// Bf element ((t*KS+ks)*64 + quad*16+lrow)*8 + j  =  W[ks*32+quad*8+j][t*16+lrow]
// ws (ushort elems): W1f @0 (131072, KS=16), Tf @131072 (32768, KS=16),
//                    W2f @163840 (32768, KS=8), W3f @196608 (8192, KS=4)
// partials (float)  @byte 409600, 8192 entries
__global__ __launch_bounds__(256)
void prep_k(const float* __restrict__ W1, const float* __restrict__ W2,
            const float* __restrict__ W3, const float* __restrict__ Th,
            unsigned short* __restrict__ ws)
{
    const int gid = blockIdx.x * 256 + threadIdx.x;
    if (gid < 131072) {                       // W1 [512][256]
        const int s = gid, k = s >> 8, n = s & 255;
        const int dst = (((n >> 4) * 16 + (k >> 5)) * 64 + ((k >> 3) & 3) * 16 + (n & 15)) * 8 + (k & 7);
        ws[dst] = f2bf(W1[s]);
    } else if (gid < 163840) {                // thetas [512][64]
        const int s = gid - 131072, k = s >> 6, n = s & 63;
        const int dst = 131072 + (((n >> 4) * 16 + (k >> 5)) * 64 + ((k >> 3) & 3) * 16 + (n & 15)) * 8 + (k & 7);
        ws[dst] = f2bf(Th[s]);
    } else if (gid < 196608) {                // W2 [256][128]
        const int s = gid - 163840, k = s >> 7, n = s & 127;
        const int dst = 163840 + (((n >> 4) * 8 + (k >> 5)) * 64 + ((k >> 3) & 3) * 16 + (n & 15)) * 8 + (k & 7);
        ws[dst] = f2bf(W2[s]);
    } else if (gid < 204800) {                // W3 [128][64]
        const int s = gid - 196608, k = s >> 6, n = s & 63;
        const int dst = 196608 + (((n >> 4) * 4 + (k >> 5)) * 64 + ((k >> 3) & 3) * 16 + (n & 15)) * 8 + (k & 7);
        ws[dst] = f2bf(W3[s]);
    }
}

// ---- final reduce: sum 8192 wave partials -> out[0] (no atomics anywhere) ----
__global__ __launch_bounds__(1024)
void reduce_k(const float* __restrict__ p, float* __restrict__ out)
{
    __shared__ float sred[16];
    const int tid = threadIdx.x;
    float s = 0.f;
    #pragma unroll
    for (int i = 0; i < 8; ++i) s += p[tid + i * 1024];
    #pragma unroll
    for (int off = 32; off > 0; off >>= 1) s += __shfl_xor(s, off);
    if ((tid & 63) == 0) sred[tid >> 6] = s;
    __syncthreads();
    if (tid < 64) {
        float v = (tid < 16) ? sred[tid] : 0.f;
        #pragma unroll
        for (int off = 8; off > 0; off >>= 1) v += __shfl_xor(v, off);
        if (tid == 0) out[0] = v * (1.0f / (float)Bn);
    }
}

// LDS 65536 B -> 2 blocks/CU, 8 waves/block = 16 waves/CU:
//  phase 0/1:   xA @0: 64 rows x 64 chunks(16B), XOR-swizzled          (65536)
//  post-p1:     h1A @0: 64 rows x 32 chunks                            (32768)
//               xt f32[64][64] @32768 (col ^ quad<<4 bank swizzle)     (16384)
//  phase 2 out: h2A @49152: 64 rows x 16 chunks                        (16384)
//  phase 3 out: lg f32[64][64] @0  (h1A dead)                          (16384)
// OCCUPANCY IS LDS-CAPPED at 16 waves/CU -> VGPRs 64..128 are FREE.
// amdgpu_waves_per_eu(4,4) pins the compiler's occupancy target so its
// pressure heuristic stops collapsing the dist-1 load pipeline (R4-R7 all
// showed VGPR=60..68 + sunk prefetches).
__global__ __launch_bounds__(512)
__attribute__((amdgpu_waves_per_eu(4, 4)))
void llp_mfma(const float* __restrict__ x,
              const float* __restrict__ label,
              const float* __restrict__ u,
              const float* __restrict__ b1, const float* __restrict__ b2,
              const float* __restrict__ b3,
              const unsigned short* __restrict__ W1f,
              const unsigned short* __restrict__ Tf,
              const unsigned short* __restrict__ W2f,
              const unsigned short* __restrict__ W3f,
              const int* __restrict__ epoch_p,
              float* __restrict__ partials)
{
    __shared__ char smem[65536];

    const int tid  = threadIdx.x;
    const int row0 = blockIdx.x * BM;
    const int w    = tid >> 6;      // wave 0..7
    const int lane = tid & 63;
    const int lrow = lane & 15;
    const int quad = lane >> 4;

    // ---- stage x tile: 8192 float4, 16 per thread, coalesced; cvt_pk packs ----
    {
        const float4* xg4 = (const float4*)(x + (size_t)row0 * Dn);
        #pragma unroll
        for (int i = 0; i < 16; ++i) {
            const int f = tid + i * 512;           // float4 idx 0..8191
            const float4 v = xg4[f];
            const int row = f >> 7, c4 = f & 127;  // 128 float4 per row
            const int kb = c4 >> 1, half = c4 & 1;
            uint2 o2;
            o2.x = cvt_pk_bf16(v.x, v.y);
            o2.y = cvt_pk_bf16(v.z, v.w);
            *(uint2*)(smem + ((row * 64 + (kb ^ (row & 7))) << 4) + (half << 3)) = o2;
        }
    }

    // ---- phase-1 weight prologue (dist-1, ks=0): issue BEFORE the barrier ----
    const int ct0  = w * 2;          // W1 col tiles 2w, 2w+1
    const int ct_x = w & 3;          // xt col tile
    const int rt_a = (w >> 2) * 2;   // xt row tiles rt_a, rt_a+1 (wave-uniform, 0 or 2)
    bf16x8 aB[4], bB[2][2], bT[2];
    #pragma unroll
    for (int t = 0; t < 2; ++t)
        bB[0][t] = *(const bf16x8*)(W1f + ((((ct0 + t) * 16 + 0) * 64 + lane) << 3));
    bT[0] = *(const bf16x8*)(Tf + (((ct_x * 16 + 0) * 64 + lane) << 3));
    __syncthreads();

    // ---- phase 1: h1 = relu(x@W1+b1) (2 ct x 4 rt) + xt (2 tiles, shared A) ----
    //      Weights double-buffered dist-1; A single-buffered (TLP covers LDS lat).
    //      RULE #20: all array indices compile-time; wave-uniform xt-row choice
    //      resolved by duplicating the loop.
    floatx4 acc[4][2], accT[2];
    #pragma unroll
    for (int t = 0; t < 2; ++t) {
        const float bv = b1[(ct0 + t) * 16 + lrow];
        #pragma unroll
        for (int rt = 0; rt < 4; ++rt) acc[rt][t] = (floatx4){bv, bv, bv, bv};
    }
    accT[0] = (floatx4){0.f, 0.f, 0.f, 0.f};
    accT[1] = (floatx4){0.f, 0.f, 0.f, 0.f};

#define P1_LOOP(XT0, XT1)                                                            \
    _Pragma("unroll")                                                                \
    for (int ks = 0; ks < 16; ++ks) {                                                \
        const int cur = ks & 1, nxt = cur ^ 1;                                       \
        if (ks < 15) {   /* weights for ks+1, issued FIRST (global, ~250cy) */       \
            const int kn = ks + 1;                                                   \
            _Pragma("unroll")                                                        \
            for (int t = 0; t < 2; ++t)                                              \
                bB[nxt][t] = *(const bf16x8*)(W1f + ((((ct0 + t) * 16 + kn) * 64 + lane) << 3)); \
            bT[nxt] = *(const bf16x8*)(Tf + (((ct_x * 16 + kn) * 64 + lane) << 3));  \
        }                                                                            \
        _Pragma("unroll")    /* A-fragments for THIS ks (LDS, ~120cy) */             \
        for (int rt = 0; rt < 4; ++rt)                                               \
            aB[rt] = *(const bf16x8*)(smem +                                         \
                (((rt * 16 + lrow) * 64 + ((ks * 4 + quad) ^ (lrow & 7))) << 4));    \
        _Pragma("unroll")                                                            \
        for (int rt = 0; rt < 4; ++rt)                                               \
            _Pragma("unroll")                                                        \
            for (int t = 0; t < 2; ++t)                                              \
                acc[rt][t] = __builtin_amdgcn_mfma_f32_16x16x32_bf16(aB[rt], bB[cur][t], acc[rt][t], 0, 0, 0); \
        accT[0] = __builtin_amdgcn_mfma_f32_16x16x32_bf16(aB[XT0], bT[cur], accT[0], 0, 0, 0); \
        accT[1] = __builtin_amdgcn_mfma_f32_16x16x32_bf16(aB[XT1], bT[cur], accT[1], 0, 0, 0); \
    }

    if (rt_a == 0) { P1_LOOP(0, 1) } else { P1_LOOP(2, 3) }
#undef P1_LOOP

    __syncthreads();   // all xA reads complete -> @0 reusable for h1A

    // h1 C-layout -> bf16 A-layout @0 ; xt f32 -> @32768 [64][64] swizzled
    #pragma unroll
    for (int rt = 0; rt < 4; ++rt) {
        #pragma unroll
        for (int t = 0; t < 2; ++t) {
            const int col = (ct0 + t) * 16 + lrow;
            #pragma unroll
            for (int g = 0; g < 4; ++g) {
                const int orow = rt * 16 + quad * 4 + g;
                *(unsigned short*)(smem +
                    ((orow * 32 + ((col >> 3) ^ (orow & 7))) << 4) + ((col & 7) << 1))
                    = f2bf(fmaxf(acc[rt][t][g], 0.0f));
            }
        }
    }
    {
        float* xtf = (float*)(smem + 32768);
        const int xcol = (ct_x * 16 + lrow) ^ (quad << 4);   // bank spread
        #pragma unroll
        for (int r = 0; r < 2; ++r)
            #pragma unroll
            for (int g = 0; g < 4; ++g)
                xtf[((rt_a + r) * 16 + quad * 4 + g) * 64 + xcol] = accT[r][g];
    }

    // ---- phase-2 weight prologue (dist-1, ks=0) + u/label: BEFORE barrier ----
    bf16x8 a2[4], b2B[2];
    b2B[0] = *(const bf16x8*)(W2f + (((w * 8 + 0) * 64 + lane) << 3));
    float upf[8], labpf[8];
    #pragma unroll
    for (int rr = 0; rr < 8; ++rr) {
        upf[rr]   = u[(size_t)(row0 + w * 8 + rr) * Kn + lane];
        labpf[rr] = label[row0 + w * 8 + rr];
    }
    __syncthreads();   // h1A + xt ready

    // ---- h2 = relu(h1@W2+b2): 1 col tile (ct=w) x 4 row-tiles ----
    floatx4 acc2[4];
    {
        const float bv = b2[w * 16 + lrow];
        #pragma unroll
        for (int rt = 0; rt < 4; ++rt) acc2[rt] = (floatx4){bv, bv, bv, bv};
    }
    #pragma unroll
    for (int ks = 0; ks < 8; ++ks) {
        const int cur = ks & 1, nxt = cur ^ 1;
        if (ks < 7)
            b2B[nxt] = *(const bf16x8*)(W2f + (((w * 8 + ks + 1) * 64 + lane) << 3));
        #pragma unroll
        for (int rt = 0; rt < 4; ++rt)
            a2[rt] = *(const bf16x8*)(smem +
                (((rt * 16 + lrow) * 32 + ((ks * 4 + quad) ^ (lrow & 7))) << 4));
        #pragma unroll
        for (int rt = 0; rt < 4; ++rt)
            acc2[rt] = __builtin_amdgcn_mfma_f32_16x16x32_bf16(a2[rt], b2B[cur], acc2[rt], 0, 0, 0);
    }
    // h2A @49152 (region dead since bar2; nobody reads it before next barrier)
    #pragma unroll
    for (int rt = 0; rt < 4; ++rt) {
        const int col = w * 16 + lrow;
        #pragma unroll
        for (int g = 0; g < 4; ++g) {
            const int orow = rt * 16 + quad * 4 + g;
            *(unsigned short*)(smem + 49152 +
                ((orow * 16 + ((col >> 3) ^ (orow & 7))) << 4) + ((col & 7) << 1))
                = f2bf(fmaxf(acc2[rt][g], 0.0f));
        }
    }

    // ---- phase-3 weight prologue: BEFORE the barrier ----
    const int ct3 = w & 3;
    const int rt3 = (w >> 2) * 2;
    bf16x8 bb[4];
    #pragma unroll
    for (int ks = 0; ks < 4; ++ks)
        bb[ks] = *(const bf16x8*)(W3f + (((ct3 * 4 + ks) * 64 + lane) << 3));
    __syncthreads();   // h2A ready; h1A reads done -> @0 free for lg

    // ---- logits = h2@W3+b3: 2 (rt,ct) tiles/wave ----
    floatx4 acc3[2];
    {
        const float bv = b3[ct3 * 16 + lrow];
        acc3[0] = (floatx4){bv, bv, bv, bv};
        acc3[1] = (floatx4){bv, bv, bv, bv};
    }
    {
        bf16x8 aa[2][4];
        #pragma unroll
        for (int ks = 0; ks < 4; ++ks)
            #pragma unroll
            for (int r = 0; r < 2; ++r) {
                const int row = (rt3 + r) * 16 + lrow;   // runtime addr math, static idx
                aa[r][ks] = *(const bf16x8*)(smem + 49152 +
                    ((row * 16 + ((ks * 4 + quad) ^ (row & 7))) << 4));
            }
        #pragma unroll
        for (int ks = 0; ks < 4; ++ks)
            #pragma unroll
            for (int r = 0; r < 2; ++r)
                acc3[r] = __builtin_amdgcn_mfma_f32_16x16x32_bf16(aa[r][ks], bb[ks], acc3[r], 0, 0, 0);
    }
    {
        float* lgf = (float*)smem;   // [64][64] @0, swizzled like xt
        const int xcol = (ct3 * 16 + lrow) ^ (quad << 4);
        #pragma unroll
        for (int r = 0; r < 2; ++r)
            #pragma unroll
            for (int g = 0; g < 4; ++g)
                lgf[((rt3 + r) * 16 + quad * 4 + g) * 64 + xcol] = acc3[r][g];
    }
    __syncthreads();

    // ---- softmax + weighted sum + loss partial: wave w -> rows w*8..+7 ----
    {
        const float* lgf = (const float*)smem;
        const float* xtf = (const float*)(smem + 32768);
        const int ep = *epoch_p;
        const float tmp = 10.0f * powf(0.01f, (float)ep * 0.001f);
        const float inv_temp = 1.0f / fmaxf(0.1f, tmp);

        float partial = 0.0f;
        #pragma unroll
        for (int rr = 0; rr < 8; ++rr) {
            const int rw = w * 8 + rr;
            const int rlane = lane ^ ((rw & 12) << 2);   // un-swizzle
            const float g = -logf(-logf(upf[rr]));
            float s = (lgf[rw * 64 + rlane] + g) * inv_temp;
            float m = s;
            #pragma unroll
            for (int off = 32; off > 0; off >>= 1)
                m = fmaxf(m, __shfl_xor(m, off));
            const float e = expf(s - m);
            float sum = e;
            float ws_ = e * xtf[rw * 64 + rlane];
            #pragma unroll
            for (int off = 32; off > 0; off >>= 1) {   // joint reduce: pipelined pair
                sum += __shfl_xor(sum, off);
                ws_ += __shfl_xor(ws_, off);
            }
            const float diff = ws_ / sum - labpf[rr];  // same value on all lanes
            partial = fmaf(diff, diff, partial);
        }
        if (lane == 0)
            partials[blockIdx.x * 8 + w] = partial;   // private slot, no atomic
    }
}

extern "C" void kernel_launch(void* const* d_in, const int* in_sizes, int n_in,
                              void* d_out, int out_size, void* d_ws, size_t ws_size,
                              hipStream_t stream) {
    const float* x      = (const float*)d_in[0];
    const float* label  = (const float*)d_in[1];
    const float* u      = (const float*)d_in[2];
    const float* W1     = (const float*)d_in[3];
    const float* b1     = (const float*)d_in[4];
    const float* W2     = (const float*)d_in[5];
    const float* b2     = (const float*)d_in[6];
    const float* W3     = (const float*)d_in[7];
    const float* b3     = (const float*)d_in[8];
    const float* thetas = (const float*)d_in[9];
    const int*   epoch  = (const int*)d_in[10];
    float* out = (float*)d_out;

    unsigned short* wsb = (unsigned short*)d_ws;
    float* partials = (float*)((char*)d_ws + 409600);

    prep_k<<<800, 256, 0, stream>>>(W1, W2, W3, thetas, wsb);
    llp_mfma<<<Bn / BM, 512, 0, stream>>>(x, label, u, b1, b2, b3,
                                          wsb, wsb + 131072, wsb + 163840, wsb + 196608,
                                          epoch, partials);
    reduce_k<<<1, 1024, 0, stream>>>(partials, out);
}

// Round 9
// 248.816 us; speedup vs baseline: 1.0342x; 1.0342x over previous
//
#include <hip/hip_runtime.h>
#include <math.h>

#define Bn  65536
#define Dn  512
#define Kn  64
#define H1n 256
#define H2n 128
#define BM  64   // rows per block (1024 blocks, 8 waves; wave = 4 row-tiles)

typedef short bf16x8 __attribute__((ext_vector_type(8)));
typedef float floatx4 __attribute__((ext_vector_type(4)));

__device__ __forceinline__ unsigned short f2bf(float f) {
    unsigned u = __builtin_bit_cast(unsigned, f);
    u += 0x7FFF + ((u >> 16) & 1);   // round-to-nearest-even
    return (unsigned short)(u >> 16);
}

// packed f32x2 -> bf16x2 (RTNE), single VALU op
__device__ __forceinline__ unsigned cvt_pk_bf16(float lo, float hi) {
    unsigned r;
    asm("v_cvt_pk_bf16_f32 %0, %1, %2" : "=v"(r) : "v"(lo), "v"(hi));
    return r;
}

// asm-issued 16B global load: issue order is program order (volatile),
// completion tracked ONLY by our hand-placed s_waitcnt vmcnt(N).
#define GLOAD(dst, ptr) \
    asm volatile("global_load_dwordx4 %0, %1, off" : "=v"(dst) : "v"(ptr))

// ---- prep: fp32 weights -> bf16 FRAGMENT-MAJOR Bf[t][ks][lane][8] ----
// Bf element ((t*KS+ks)*64 + quad*16+lrow)*8 + j  =  W[ks*32+quad*8+j][t*16+lrow]
// ws (ushort elems): W1f @0 (131072, KS=16), Tf @131072 (32768, KS=16),
//                    W2f @163840 (32768, KS=8), W3f @196608 (8192, KS=4)
// partials (float)  @byte 409600, 8192 entries
__global__ __launch_bounds__(256)
void prep_k(const float* __restrict__ W1, const float* __restrict__ W2,
            const float* __restrict__ W3, const float* __restrict__ Th,
            unsigned short* __restrict__ ws)
{
    const int gid = blockIdx.x * 256 + threadIdx.x;
    if (gid < 131072) {                       // W1 [512][256]
        const int s = gid, k = s >> 8, n = s & 255;
        const int dst = (((n >> 4) * 16 + (k >> 5)) * 64 + ((k >> 3) & 3) * 16 + (n & 15)) * 8 + (k & 7);
        ws[dst] = f2bf(W1[s]);
    } else if (gid < 163840) {                // thetas [512][64]
        const int s = gid - 131072, k = s >> 6, n = s & 63;
        const int dst = 131072 + (((n >> 4) * 16 + (k >> 5)) * 64 + ((k >> 3) & 3) * 16 + (n & 15)) * 8 + (k & 7);
        ws[dst] = f2bf(Th[s]);
    } else if (gid < 196608) {                // W2 [256][128]
        const int s = gid - 163840, k = s >> 7, n = s & 127;
        const int dst = 163840 + (((n >> 4) * 8 + (k >> 5)) * 64 + ((k >> 3) & 3) * 16 + (n & 15)) * 8 + (k & 7);
        ws[dst] = f2bf(W2[s]);
    } else if (gid < 204800) {                // W3 [128][64]
        const int s = gid - 196608, k = s >> 6, n = s & 63;
        const int dst = 196608 + (((n >> 4) * 4 + (k >> 5)) * 64 + ((k >> 3) & 3) * 16 + (n & 15)) * 8 + (k & 7);
        ws[dst] = f2bf(W3[s]);
    }
}

// ---- final reduce: sum 8192 wave partials -> out[0] (no atomics anywhere) ----
__global__ __launch_bounds__(1024)
void reduce_k(const float* __restrict__ p, float* __restrict__ out)
{
    __shared__ float sred[16];
    const int tid = threadIdx.x;
    float s = 0.f;
    #pragma unroll
    for (int i = 0; i < 8; ++i) s += p[tid + i * 1024];
    #pragma unroll
    for (int off = 32; off > 0; off >>= 1) s += __shfl_xor(s, off);
    if ((tid & 63) == 0) sred[tid >> 6] = s;
    __syncthreads();
    if (tid < 64) {
        float v = (tid < 16) ? sred[tid] : 0.f;
        #pragma unroll
        for (int off = 8; off > 0; off >>= 1) v += __shfl_xor(v, off);
        if (tid == 0) out[0] = v * (1.0f / (float)Bn);
    }
}

// LDS 65536 B -> 2 blocks/CU, 8 waves/block = 16 waves/CU.
// K-loop weight streams are inline-asm global_load_dwordx4 with COUNTED
// vmcnt (never 0 mid-loop): ring-3, dist-2. Barriers crossed by prefetches
// are raw s_barrier + lgkmcnt(0) (no vmcnt drain). All compiler-tracked
// VMEM first-uses are kept OUTSIDE the two prefetch windows so the
// compiler never inserts vmcnt(0) inside them.
__global__ __launch_bounds__(512)
__attribute__((amdgpu_waves_per_eu(4, 4)))
void llp_mfma(const float* __restrict__ x,
              const float* __restrict__ label,
              const float* __restrict__ u,
              const float* __restrict__ b1, const float* __restrict__ b2,
              const float* __restrict__ b3,
              const unsigned short* __restrict__ W1f,
              const unsigned short* __restrict__ Tf,
              const unsigned short* __restrict__ W2f,
              const unsigned short* __restrict__ W3f,
              const int* __restrict__ epoch_p,
              float* __restrict__ partials)
{
    __shared__ char smem[65536];

    const int tid  = threadIdx.x;
    const int row0 = blockIdx.x * BM;
    const int w    = tid >> 6;      // wave 0..7
    const int lane = tid & 63;
    const int lrow = lane & 15;
    const int quad = lane >> 4;

    const int ct0  = w * 2;          // W1 col tiles 2w, 2w+1
    const int ct_x = w & 3;          // xt col tile
    const int rt_a = (w >> 2) * 2;   // xt row tiles (wave-uniform, 0 or 2)
    const int ct3  = w & 3;
    const int rt3  = (w >> 2) * 2;

    // ---- bias loads FIRST: their compiler vmcnt waits land here, outside
    //      the asm-prefetch windows ----
    const float b1v0 = b1[(ct0 + 0) * 16 + lrow];
    const float b1v1 = b1[(ct0 + 1) * 16 + lrow];
    const float b2v  = b2[w * 16 + lrow];
    const float b3v  = b3[ct3 * 16 + lrow];

    // ---- stage x tile: 8192 float4, 16 per thread, coalesced; cvt_pk packs ----
    {
        const float4* xg4 = (const float4*)(x + (size_t)row0 * Dn);
        #pragma unroll
        for (int i = 0; i < 16; ++i) {
            const int f = tid + i * 512;           // float4 idx 0..8191
            const float4 v = xg4[f];
            const int row = f >> 7, c4 = f & 127;  // 128 float4 per row
            const int kb = c4 >> 1, half = c4 & 1;
            uint2 o2;
            o2.x = cvt_pk_bf16(v.x, v.y);
            o2.y = cvt_pk_bf16(v.z, v.w);
            *(uint2*)(smem + ((row * 64 + (kb ^ (row & 7))) << 4) + (half << 3)) = o2;
        }
    }

    // ---- P1 accumulator init BEFORE the prologue (uses b1v, no VMEM after) ----
    floatx4 acc[4][2], accT[2];
    #pragma unroll
    for (int rt = 0; rt < 4; ++rt) {
        acc[rt][0] = (floatx4){b1v0, b1v0, b1v0, b1v0};
        acc[rt][1] = (floatx4){b1v1, b1v1, b1v1, b1v1};
    }
    accT[0] = (floatx4){0.f, 0.f, 0.f, 0.f};
    accT[1] = (floatx4){0.f, 0.f, 0.f, 0.f};

    // ---- P1 weight prologue: sets 0,1 into ring slots 0,1 (6 loads in flight) ----
    bf16x8 aB[4], bB[3][2], bT[3];
    GLOAD(bB[0][0], W1f + ((((ct0 + 0) * 16 + 0) * 64 + lane) << 3));
    GLOAD(bB[0][1], W1f + ((((ct0 + 1) * 16 + 0) * 64 + lane) << 3));
    GLOAD(bT[0],    Tf  + (((ct_x * 16 + 0) * 64 + lane) << 3));
    GLOAD(bB[1][0], W1f + ((((ct0 + 0) * 16 + 1) * 64 + lane) << 3));
    GLOAD(bB[1][1], W1f + ((((ct0 + 1) * 16 + 1) * 64 + lane) << 3));
    GLOAD(bT[1],    Tf  + (((ct_x * 16 + 1) * 64 + lane) << 3));

    // BAR1: raw barrier — drain LDS writes only, keep the 6 loads in flight
    asm volatile("s_waitcnt lgkmcnt(0)" ::: "memory");
    __builtin_amdgcn_s_barrier();

    // ---- phase 1: h1 = relu(x@W1+b1) (2 ct x 4 rt) + xt (2 tiles, shared A) ----
#define P1_LOOP(XT0, XT1)                                                            \
    _Pragma("unroll")                                                                \
    for (int ks = 0; ks < 16; ++ks) {                                                \
        const int wsl = ks % 3;                                                      \
        if (ks < 14) {   /* issue set ks+2 into the free ring slot, FIRST */         \
            const int kn = ks + 2, sl = kn % 3;                                      \
            GLOAD(bB[sl][0], W1f + ((((ct0 + 0) * 16 + kn) * 64 + lane) << 3));      \
            GLOAD(bB[sl][1], W1f + ((((ct0 + 1) * 16 + kn) * 64 + lane) << 3));      \
            GLOAD(bT[sl],    Tf  + (((ct_x * 16 + kn) * 64 + lane) << 3));           \
        }                                                                            \
        __builtin_amdgcn_sched_barrier(0);                                           \
        _Pragma("unroll")    /* A-fragments for THIS ks (LDS, lgkmcnt-tracked) */    \
        for (int rt = 0; rt < 4; ++rt)                                               \
            aB[rt] = *(const bf16x8*)(smem +                                         \
                (((rt * 16 + lrow) * 64 + ((ks * 4 + quad) ^ (lrow & 7))) << 4));    \
        if (ks < 14)      { asm volatile("s_waitcnt vmcnt(6)" ::: "memory"); }       \
        else if (ks == 14){ asm volatile("s_waitcnt vmcnt(3)" ::: "memory"); }       \
        else              { asm volatile("s_waitcnt vmcnt(0)" ::: "memory"); }       \
        __builtin_amdgcn_sched_barrier(0);                                           \
        _Pragma("unroll")                                                            \
        for (int rt = 0; rt < 4; ++rt) {                                             \
            acc[rt][0] = __builtin_amdgcn_mfma_f32_16x16x32_bf16(aB[rt], bB[wsl][0], acc[rt][0], 0, 0, 0); \
            acc[rt][1] = __builtin_amdgcn_mfma_f32_16x16x32_bf16(aB[rt], bB[wsl][1], acc[rt][1], 0, 0, 0); \
        }                                                                            \
        accT[0] = __builtin_amdgcn_mfma_f32_16x16x32_bf16(aB[XT0], bT[wsl], accT[0], 0, 0, 0); \
        accT[1] = __builtin_amdgcn_mfma_f32_16x16x32_bf16(aB[XT1], bT[wsl], accT[1], 0, 0, 0); \
    }

    if (rt_a == 0) { P1_LOOP(0, 1) } else { P1_LOOP(2, 3) }
#undef P1_LOOP

    __syncthreads();   // xA reads complete -> @0 reusable (vmcnt already 0)

    // h1 C-layout -> bf16 A-layout @0 ; xt f32 -> @32768 [64][64] swizzled
    #pragma unroll
    for (int rt = 0; rt < 4; ++rt) {
        #pragma unroll
        for (int t = 0; t < 2; ++t) {
            const int col = (ct0 + t) * 16 + lrow;
            #pragma unroll
            for (int g = 0; g < 4; ++g) {
                const int orow = rt * 16 + quad * 4 + g;
                *(unsigned short*)(smem +
                    ((orow * 32 + ((col >> 3) ^ (orow & 7))) << 4) + ((col & 7) << 1))
                    = f2bf(fmaxf(acc[rt][t][g], 0.0f));
            }
        }
    }
    {
        float* xtf = (float*)(smem + 32768);
        const int xcol = (ct_x * 16 + lrow) ^ (quad << 4);   // bank spread
        #pragma unroll
        for (int r = 0; r < 2; ++r)
            #pragma unroll
            for (int g = 0; g < 4; ++g)
                xtf[((rt_a + r) * 16 + quad * 4 + g) * 64 + xcol] = accT[r][g];
    }

    // ---- P2 acc init (b2v already in reg — no VMEM) + weight prologue ----
    floatx4 acc2[4];
    #pragma unroll
    for (int rt = 0; rt < 4; ++rt) acc2[rt] = (floatx4){b2v, b2v, b2v, b2v};
    bf16x8 a2[4], b2B[3];
    GLOAD(b2B[0], W2f + (((w * 8 + 0) * 64 + lane) << 3));
    GLOAD(b2B[1], W2f + (((w * 8 + 1) * 64 + lane) << 3));

    // BAR3: raw barrier — h1A/xt ds_writes drained, 2 loads stay in flight
    asm volatile("s_waitcnt lgkmcnt(0)" ::: "memory");
    __builtin_amdgcn_s_barrier();

    // ---- h2 = relu(h1@W2+b2): 1 col tile (ct=w) x 4 row-tiles ----
    #pragma unroll
    for (int ks = 0; ks < 8; ++ks) {
        const int wsl = ks % 3;
        if (ks < 6) {
            const int kn = ks + 2, sl = kn % 3;
            GLOAD(b2B[sl], W2f + (((w * 8 + kn) * 64 + lane) << 3));
        }
        __builtin_amdgcn_sched_barrier(0);
        #pragma unroll
        for (int rt = 0; rt < 4; ++rt)
            a2[rt] = *(const bf16x8*)(smem +
                (((rt * 16 + lrow) * 32 + ((ks * 4 + quad) ^ (lrow & 7))) << 4));
        if (ks < 6)      { asm volatile("s_waitcnt vmcnt(2)" ::: "memory"); }
        else if (ks == 6){ asm volatile("s_waitcnt vmcnt(1)" ::: "memory"); }
        else             { asm volatile("s_waitcnt vmcnt(0)" ::: "memory"); }
        __builtin_amdgcn_sched_barrier(0);
        #pragma unroll
        for (int rt = 0; rt < 4; ++rt)
            acc2[rt] = __builtin_amdgcn_mfma_f32_16x16x32_bf16(a2[rt], b2B[wsl], acc2[rt], 0, 0, 0);
    }

    // ---- u/label prefetch AFTER the P2 window (compiler-tracked, safe) ----
    float upf[8], labpf[8];
    #pragma unroll
    for (int rr = 0; rr < 8; ++rr) {
        upf[rr]   = u[(size_t)(row0 + w * 8 + rr) * Kn + lane];
        labpf[rr] = label[row0 + w * 8 + rr];
    }

    // h2A @49152 (region dead since BAR3; nobody reads it before next barrier)
    #pragma unroll
    for (int rt = 0; rt < 4; ++rt) {
        const int col = w * 16 + lrow;
        #pragma unroll
        for (int g = 0; g < 4; ++g) {
            const int orow = rt * 16 + quad * 4 + g;
            *(unsigned short*)(smem + 49152 +
                ((orow * 16 + ((col >> 3) ^ (orow & 7))) << 4) + ((col & 7) << 1))
                = f2bf(fmaxf(acc2[rt][g], 0.0f));
        }
    }

    // ---- phase-3 weight prologue (compiler loads, outside asm windows) ----
    bf16x8 bb[4];
    #pragma unroll
    for (int ks = 0; ks < 4; ++ks)
        bb[ks] = *(const bf16x8*)(W3f + (((ct3 * 4 + ks) * 64 + lane) << 3));
    __syncthreads();   // h2A ready; h1A reads done -> @0 free for lg

    // ---- logits = h2@W3+b3: 2 (rt,ct) tiles/wave ----
    floatx4 acc3[2];
    acc3[0] = (floatx4){b3v, b3v, b3v, b3v};
    acc3[1] = (floatx4){b3v, b3v, b3v, b3v};
    {
        bf16x8 aa[2][4];
        #pragma unroll
        for (int ks = 0; ks < 4; ++ks)
            #pragma unroll
            for (int r = 0; r < 2; ++r) {
                const int row = (rt3 + r) * 16 + lrow;   // runtime addr math, static idx
                aa[r][ks] = *(const bf16x8*)(smem + 49152 +
                    ((row * 16 + ((ks * 4 + quad) ^ (row & 7))) << 4));
            }
        #pragma unroll
        for (int ks = 0; ks < 4; ++ks)
            #pragma unroll
            for (int r = 0; r < 2; ++r)
                acc3[r] = __builtin_amdgcn_mfma_f32_16x16x32_bf16(aa[r][ks], bb[ks], acc3[r], 0, 0, 0);
    }
    {
        float* lgf = (float*)smem;   // [64][64] @0, swizzled like xt
        const int xcol = (ct3 * 16 + lrow) ^ (quad << 4);
        #pragma unroll
        for (int r = 0; r < 2; ++r)
            #pragma unroll
            for (int g = 0; g < 4; ++g)
                lgf[((rt3 + r) * 16 + quad * 4 + g) * 64 + xcol] = acc3[r][g];
    }
    __syncthreads();

    // ---- softmax + weighted sum + loss partial: wave w -> rows w*8..+7 ----
    {
        const float* lgf = (const float*)smem;
        const float* xtf = (const float*)(smem + 32768);
        const int ep = *epoch_p;
        const float tmp = 10.0f * powf(0.01f, (float)ep * 0.001f);
        const float inv_temp = 1.0f / fmaxf(0.1f, tmp);

        float partial = 0.0f;
        #pragma unroll
        for (int rr = 0; rr < 8; ++rr) {
            const int rw = w * 8 + rr;
            const int rlane = lane ^ ((rw & 12) << 2);   // un-swizzle
            const float g = -logf(-logf(upf[rr]));
            float s = (lgf[rw * 64 + rlane] + g) * inv_temp;
            float m = s;
            #pragma unroll
            for (int off = 32; off > 0; off >>= 1)
                m = fmaxf(m, __shfl_xor(m, off));
            const float e = expf(s - m);
            float sum = e;
            float ws_ = e * xtf[rw * 64 + rlane];
            #pragma unroll
            for (int off = 32; off > 0; off >>= 1) {   // joint reduce: pipelined pair
                sum += __shfl_xor(sum, off);
                ws_ += __shfl_xor(ws_, off);
            }
            const float diff = ws_ / sum - labpf[rr];  // same value on all lanes
            partial = fmaf(diff, diff, partial);
        }
        if (lane == 0)
            partials[blockIdx.x * 8 + w] = partial;   // private slot, no atomic
    }
}

extern "C" void kernel_launch(void* const* d_in, const int* in_sizes, int n_in,
                              void* d_out, int out_size, void* d_ws, size_t ws_size,
                              hipStream_t stream) {
    const float* x      = (const float*)d_in[0];
    const float* label  = (const float*)d_in[1];
    const float* u      = (const float*)d_in[2];
    const float* W1     = (const float*)d_in[3];
    const float* b1     = (const float*)d_in[4];
    const float* W2     = (const float*)d_in[5];
    const float* b2     = (const float*)d_in[6];
    const float* W3     = (const float*)d_in[7];
    const float* b3     = (const float*)d_in[8];
    const float* thetas = (const float*)d_in[9];
    const int*   epoch  = (const int*)d_in[10];
    float* out = (float*)d_out;

    unsigned short* wsb = (unsigned short*)d_ws;
    float* partials = (float*)((char*)d_ws + 409600);

    prep_k<<<800, 256, 0, stream>>>(W1, W2, W3, thetas, wsb);
    llp_mfma<<<Bn / BM, 512, 0, stream>>>(x, label, u, b1, b2, b3,
                                          wsb, wsb + 131072, wsb + 163840, wsb + 196608,
                                          epoch, partials);
    reduce_k<<<1, 1024, 0, stream>>>(partials, out);
}